// Round 2
// baseline (336.740 us; speedup 1.0000x reference)
//
#include <hip/hip_runtime.h>
#include <hip/hip_bf16.h>

// ---- problem constants ----
// B=2, T=2048, D=1024, H=16, Hd=64. Inputs/outputs float32; compute in bf16 MFMA.

typedef __bf16 bf16;
typedef bf16 bf16x8 __attribute__((ext_vector_type(8)));
typedef float f32x4 __attribute__((ext_vector_type(4)));

#define MFMA16(a, b, c) __builtin_amdgcn_mfma_f32_16x16x32_bf16((a), (b), (c), 0, 0, 0)

static constexpr int D_MODEL = 1024;
static constexpr int NH = 16;
static constexpr int HD = 64;
static constexpr int SEQ = 2048;
static constexpr int NB = 2;
static constexpr float QSCALE = 0.125f * 1.44269504088896340736f; // 1/sqrt(64) * log2(e)
static constexpr float NEGBIG = -1.0e30f;   // finite "-inf": no inf-inf NaN risk

__device__ __forceinline__ bf16x8 cvt8(const float* p) {
    float4 u0 = *(const float4*)p;
    float4 u1 = *(const float4*)(p + 4);
    bf16x8 v = { (bf16)u0.x, (bf16)u0.y, (bf16)u0.z, (bf16)u0.w,
                 (bf16)u1.x, (bf16)u1.y, (bf16)u1.z, (bf16)u1.w };
    return v;
}

// ---------------------------------------------------------------------------
// Kernel 1: QKV projection.  C[m][n] = sum_k x[m][k]*qkv_w[n][k] + qkv_b[n]
// 64x64 tile, BK=32, 4 waves in 2x2 (each wave 32x32 via 2x2 MFMA 16x16x32).
// Epilogue scatters bf16 into Qb/Kb/Vb [B,H,T,64]; Q pre-scaled by QSCALE.
// ---------------------------------------------------------------------------
__global__ __launch_bounds__(256)
void k_qkv(const float* __restrict__ x, const float* __restrict__ w,
           const float* __restrict__ bias,
           bf16* __restrict__ Qb, bf16* __restrict__ Kb, bf16* __restrict__ Vb)
{
    __shared__ bf16 Xs[64][40];
    __shared__ bf16 Ws[64][40];

    const int tid  = threadIdx.x;
    const int wv   = tid >> 6;
    const int lane = tid & 63;
    const int lr   = lane & 15;
    const int lk   = lane >> 4;
    const int wm   = wv >> 1, wn = wv & 1;
    const int m0   = blockIdx.x * 64;
    const int n0   = blockIdx.y * 64;

    const int ldRow = tid >> 2;          // 0..63
    const int ldCol = (tid & 3) * 8;     // 0,8,16,24

    f32x4 acc[2][2] = {};

    for (int kt = 0; kt < 1024; kt += 32) {
        __syncthreads();
        *(bf16x8*)&Xs[ldRow][ldCol] = cvt8(&x[(size_t)(m0 + ldRow) * 1024 + kt + ldCol]);
        *(bf16x8*)&Ws[ldRow][ldCol] = cvt8(&w[(size_t)(n0 + ldRow) * 1024 + kt + ldCol]);
        __syncthreads();

        bf16x8 a0 = *(const bf16x8*)&Xs[wm * 32      + lr][lk * 8];
        bf16x8 a1 = *(const bf16x8*)&Xs[wm * 32 + 16 + lr][lk * 8];
        bf16x8 b0 = *(const bf16x8*)&Ws[wn * 32      + lr][lk * 8];
        bf16x8 b1 = *(const bf16x8*)&Ws[wn * 32 + 16 + lr][lk * 8];

        acc[0][0] = MFMA16(a0, b0, acc[0][0]);
        acc[0][1] = MFMA16(a0, b1, acc[0][1]);
        acc[1][0] = MFMA16(a1, b0, acc[1][0]);
        acc[1][1] = MFMA16(a1, b1, acc[1][1]);
    }

    // C/D layout (m89-verified): col = lane&15, row = (lane>>4)*4 + reg
    #pragma unroll
    for (int i = 0; i < 2; i++) {
        #pragma unroll
        for (int j = 0; j < 2; j++) {
            #pragma unroll
            for (int r = 0; r < 4; r++) {
                int gm = m0 + wm * 32 + i * 16 + lk * 4 + r;
                int gn = n0 + wn * 32 + j * 16 + lr;
                float v = acc[i][j][r] + bias[gn];
                int sel = gn >> 10;
                int rem = gn & 1023;
                int h   = rem >> 6;
                int hd  = rem & 63;
                int bb  = gm >> 11;
                int t   = gm & 2047;
                int idx = ((bb * NH + h) * SEQ + t) * HD + hd;
                if (sel == 0)       Qb[idx] = (bf16)(v * QSCALE);
                else if (sel == 1)  Kb[idx] = (bf16)v;
                else                Vb[idx] = (bf16)v;
            }
        }
    }
}

// ---------------------------------------------------------------------------
// Kernel 2: causal flash attention (all-bf16 workspace tensors).
// Grid: (T/64 q-tiles, B*H). 4 waves; wave w owns q-rows [w*16, w*16+16).
// ---------------------------------------------------------------------------
__global__ __launch_bounds__(256)
void k_attn(const bf16* __restrict__ Qb, const bf16* __restrict__ Kb,
            const bf16* __restrict__ Vb, bf16* __restrict__ AO)
{
    __shared__ bf16 Qs [64][72];
    __shared__ bf16 Ks [64][72];
    __shared__ bf16 Vts[64][72];  // V transposed: [hd][kk]
    __shared__ bf16 Ps [64][72];  // P tile [q][kk]

    const int tid  = threadIdx.x;
    const int wv   = tid >> 6;
    const int lane = tid & 63;
    const int lr   = lane & 15;
    const int lk   = lane >> 4;
    const int qt   = blockIdx.x;
    const int bh   = blockIdx.y;

    const bf16* Qp = Qb + (size_t)bh * SEQ * HD;
    const bf16* Kp = Kb + (size_t)bh * SEQ * HD;
    const bf16* Vp = Vb + (size_t)bh * SEQ * HD;

    for (int i = tid; i < 512; i += 256) {
        int r = i >> 3, c = (i & 7) * 8;
        *(bf16x8*)&Qs[r][c] = *(const bf16x8*)&Qp[(qt * 64 + r) * HD + c];
    }
    __syncthreads();

    bf16x8 qa[2];
    qa[0] = *(const bf16x8*)&Qs[wv * 16 + lr][0 * 32 + lk * 8];
    qa[1] = *(const bf16x8*)&Qs[wv * 16 + lr][1 * 32 + lk * 8];

    f32x4 o[4] = {};
    float mrow[4] = { NEGBIG, NEGBIG, NEGBIG, NEGBIG };
    float lrow[4] = {};

    for (int kt = 0; kt <= qt; kt++) {
        __syncthreads();
        for (int i = tid; i < 512; i += 256) {
            int r = i >> 3, c = (i & 7) * 8;
            *(bf16x8*)&Ks[r][c] = *(const bf16x8*)&Kp[(kt * 64 + r) * HD + c];
            bf16x8 vv = *(const bf16x8*)&Vp[(kt * 64 + r) * HD + c];
            #pragma unroll
            for (int e = 0; e < 8; e++) Vts[c + e][r] = vv[e];
        }
        __syncthreads();

        // S = Q K^T (16x64 strip per wave); softmax scale folded into Q (log2 domain)
        f32x4 s[4] = {};
        #pragma unroll
        for (int j = 0; j < 4; j++) {
            #pragma unroll
            for (int c = 0; c < 2; c++) {
                bf16x8 kb = *(const bf16x8*)&Ks[j * 16 + lr][c * 32 + lk * 8];
                s[j] = MFMA16(qa[c], kb, s[j]);
            }
        }

        if (kt == qt) {   // causal mask, diagonal tile only
            int qloc = wv * 16 + lk * 4;
            #pragma unroll
            for (int j = 0; j < 4; j++) {
                int kloc = j * 16 + lr;
                #pragma unroll
                for (int r = 0; r < 4; r++)
                    if (kloc > qloc + r) s[j][r] = NEGBIG;
            }
        }

        // online softmax; row (lk*4+r) lives on the 16 lanes sharing lk
        #pragma unroll
        for (int r = 0; r < 4; r++) {
            float v = fmaxf(fmaxf(s[0][r], s[1][r]), fmaxf(s[2][r], s[3][r]));
            v = fmaxf(v, __shfl_xor(v, 1));
            v = fmaxf(v, __shfl_xor(v, 2));
            v = fmaxf(v, __shfl_xor(v, 4));
            v = fmaxf(v, __shfl_xor(v, 8));
            float mnew  = fmaxf(mrow[r], v);
            float alpha = exp2f(mrow[r] - mnew);
            mrow[r] = mnew;
            float rsum = 0.f;
            #pragma unroll
            for (int j = 0; j < 4; j++) {
                float p = exp2f(s[j][r] - mnew);
                s[j][r] = p;
                rsum += p;
            }
            rsum += __shfl_xor(rsum, 1);
            rsum += __shfl_xor(rsum, 2);
            rsum += __shfl_xor(rsum, 4);
            rsum += __shfl_xor(rsum, 8);
            lrow[r] = lrow[r] * alpha + rsum;
            #pragma unroll
            for (int jh = 0; jh < 4; jh++) o[jh][r] *= alpha;
        }

        // P (C-layout) -> LDS [q][kk] for the PV A-operand
        #pragma unroll
        for (int j = 0; j < 4; j++)
            #pragma unroll
            for (int r = 0; r < 4; r++)
                Ps[wv * 16 + lk * 4 + r][j * 16 + lr] = (bf16)s[j][r];
        __syncthreads();

        // O += P V   (A = Ps rows, B = Vts rows = V^T)
        #pragma unroll
        for (int c = 0; c < 2; c++) {
            bf16x8 pa = *(const bf16x8*)&Ps[wv * 16 + lr][c * 32 + lk * 8];
            #pragma unroll
            for (int jh = 0; jh < 4; jh++) {
                bf16x8 vb = *(const bf16x8*)&Vts[jh * 16 + lr][c * 32 + lk * 8];
                o[jh] = MFMA16(pa, vb, o[jh]);
            }
        }
    }

    // epilogue: AO[b, t, h*64+hd] = O / l   (bf16 workspace, [B,T,D] layout)
    const int b_ = bh >> 4, h_ = bh & 15;
    #pragma unroll
    for (int r = 0; r < 4; r++) {
        float inv = 1.0f / lrow[r];
        int q = qt * 64 + wv * 16 + lk * 4 + r;
        size_t base = ((size_t)(b_ * SEQ + q)) * D_MODEL + h_ * HD;
        #pragma unroll
        for (int jh = 0; jh < 4; jh++)
            AO[base + jh * 16 + lr] = (bf16)(o[jh][r] * inv);
    }
}

// ---------------------------------------------------------------------------
// Kernel 3: output projection. out[m][n] = sum_k AO[m][k]*out_w[n][k] + out_b[n]
// A is bf16 workspace; W/bias are f32; out is f32.
// ---------------------------------------------------------------------------
__global__ __launch_bounds__(256)
void k_oproj(const bf16* __restrict__ a, const float* __restrict__ w,
             const float* __restrict__ bias, float* __restrict__ out)
{
    __shared__ bf16 As[64][40];
    __shared__ bf16 Ws[64][40];

    const int tid  = threadIdx.x;
    const int wv   = tid >> 6;
    const int lane = tid & 63;
    const int lr   = lane & 15;
    const int lk   = lane >> 4;
    const int wm   = wv >> 1, wn = wv & 1;
    const int m0   = blockIdx.x * 64;
    const int n0   = blockIdx.y * 64;

    const int ldRow = tid >> 2;
    const int ldCol = (tid & 3) * 8;

    f32x4 acc[2][2] = {};

    for (int kt = 0; kt < 1024; kt += 32) {
        __syncthreads();
        *(bf16x8*)&As[ldRow][ldCol] = *(const bf16x8*)&a[(size_t)(m0 + ldRow) * 1024 + kt + ldCol];
        *(bf16x8*)&Ws[ldRow][ldCol] = cvt8(&w[(size_t)(n0 + ldRow) * 1024 + kt + ldCol]);
        __syncthreads();

        bf16x8 a0 = *(const bf16x8*)&As[wm * 32      + lr][lk * 8];
        bf16x8 a1 = *(const bf16x8*)&As[wm * 32 + 16 + lr][lk * 8];
        bf16x8 b0 = *(const bf16x8*)&Ws[wn * 32      + lr][lk * 8];
        bf16x8 b1 = *(const bf16x8*)&Ws[wn * 32 + 16 + lr][lk * 8];

        acc[0][0] = MFMA16(a0, b0, acc[0][0]);
        acc[0][1] = MFMA16(a0, b1, acc[0][1]);
        acc[1][0] = MFMA16(a1, b0, acc[1][0]);
        acc[1][1] = MFMA16(a1, b1, acc[1][1]);
    }

    #pragma unroll
    for (int i = 0; i < 2; i++) {
        #pragma unroll
        for (int j = 0; j < 2; j++) {
            #pragma unroll
            for (int r = 0; r < 4; r++) {
                int gm = m0 + wm * 32 + i * 16 + lk * 4 + r;
                int gn = n0 + wn * 32 + j * 16 + lr;
                out[(size_t)gm * 1024 + gn] = acc[i][j][r] + bias[gn];
            }
        }
    }
}

// ---------------------------------------------------------------------------
extern "C" void kernel_launch(void* const* d_in, const int* in_sizes, int n_in,
                              void* d_out, int out_size, void* d_ws, size_t ws_size,
                              hipStream_t stream)
{
    const float* x     = (const float*)d_in[0];
    const float* qkv_w = (const float*)d_in[1];
    const float* qkv_b = (const float*)d_in[2];
    const float* out_w = (const float*)d_in[3];
    const float* out_b = (const float*)d_in[4];
    float* out = (float*)d_out;

    // workspace: Qb | Kb | Vb | AO, each B*H*T*HD = 4,194,304 bf16 (8 MB) -> 32 MB
    const size_t SZ = (size_t)NB * NH * SEQ * HD;
    bf16* Qb = (bf16*)d_ws;
    bf16* Kb = Qb + SZ;
    bf16* Vb = Kb + SZ;
    bf16* AO = Vb + SZ;

    hipLaunchKernelGGL(k_qkv, dim3(64, 48), dim3(256), 0, stream,
                       x, qkv_w, qkv_b, Qb, Kb, Vb);
    hipLaunchKernelGGL(k_attn, dim3(32, 32), dim3(256), 0, stream,
                       Qb, Kb, Vb, AO);
    hipLaunchKernelGGL(k_oproj, dim3(64, 16), dim3(256), 0, stream,
                       AO, out_w, out_b, out);
}

// Round 3
// 284.195 us; speedup vs baseline: 1.1849x; 1.1849x over previous
//
#include <hip/hip_runtime.h>
#include <hip/hip_bf16.h>

// B=2, T=2048, D=1024, H=16, Hd=64. Inputs/outputs f32; compute bf16 MFMA.

typedef __bf16 bf16;
typedef bf16 bf16x8 __attribute__((ext_vector_type(8)));
typedef float f32x4 __attribute__((ext_vector_type(4)));

#define MFMA16(a, b, c) __builtin_amdgcn_mfma_f32_16x16x32_bf16((a), (b), (c), 0, 0, 0)

static constexpr int D_MODEL = 1024;
static constexpr int NH = 16;
static constexpr int HD = 64;
static constexpr int SEQ = 2048;
static constexpr int NB = 2;
static constexpr float QSCALE = 0.125f * 1.44269504088896340736f; // 1/sqrt(64)*log2(e)
static constexpr float NEGBIG = -1.0e30f;

__device__ __forceinline__ bf16x8 cvt8(const float* p) {
    float4 u0 = *(const float4*)p;
    float4 u1 = *(const float4*)(p + 4);
    bf16x8 v = { (bf16)u0.x, (bf16)u0.y, (bf16)u0.z, (bf16)u0.w,
                 (bf16)u1.x, (bf16)u1.y, (bf16)u1.z, (bf16)u1.w };
    return v;
}

// ---------------------------------------------------------------------------
// Kernel 1: QKV projection, 128x128 tile, BK=32, 4 waves 2x2 (64x64 per wave,
// 4x4 MFMA acc). f32->bf16 conversion in staging. Epilogue scatters:
//   Q -> [B,H,T,64] (pre-scaled), K -> [B,H,T,64], V -> TRANSPOSED [B,H,64,T].
// ---------------------------------------------------------------------------
__global__ __launch_bounds__(256)
void k_qkv(const float* __restrict__ x, const float* __restrict__ w,
           const float* __restrict__ bias,
           bf16* __restrict__ Qb, bf16* __restrict__ Kb, bf16* __restrict__ VbT)
{
    __shared__ bf16 As[128][40];
    __shared__ bf16 Ws[128][40];

    const int tid  = threadIdx.x;
    const int wv   = tid >> 6;
    const int lane = tid & 63;
    const int lr   = lane & 15;
    const int lk   = lane >> 4;
    const int wm   = wv >> 1, wn = wv & 1;
    const int m0   = blockIdx.x * 128;
    const int n0   = blockIdx.y * 128;

    const int ldRow = tid >> 2;          // 0..63
    const int ldCh  = (tid & 3) * 8;     // 0,8,16,24

    f32x4 acc[4][4] = {};

    for (int kt = 0; kt < 1024; kt += 32) {
        __syncthreads();
        *(bf16x8*)&As[ldRow     ][ldCh] = cvt8(&x[(size_t)(m0 + ldRow     ) * 1024 + kt + ldCh]);
        *(bf16x8*)&As[ldRow + 64][ldCh] = cvt8(&x[(size_t)(m0 + ldRow + 64) * 1024 + kt + ldCh]);
        *(bf16x8*)&Ws[ldRow     ][ldCh] = cvt8(&w[(size_t)(n0 + ldRow     ) * 1024 + kt + ldCh]);
        *(bf16x8*)&Ws[ldRow + 64][ldCh] = cvt8(&w[(size_t)(n0 + ldRow + 64) * 1024 + kt + ldCh]);
        __syncthreads();

        bf16x8 a[4], b[4];
        #pragma unroll
        for (int i = 0; i < 4; i++) {
            a[i] = *(const bf16x8*)&As[wm * 64 + i * 16 + lr][lk * 8];
            b[i] = *(const bf16x8*)&Ws[wn * 64 + i * 16 + lr][lk * 8];
        }
        #pragma unroll
        for (int i = 0; i < 4; i++)
            #pragma unroll
            for (int j = 0; j < 4; j++)
                acc[i][j] = MFMA16(a[i], b[j], acc[i][j]);
    }

    // C/D layout: col = lane&15, row = (lane>>4)*4 + reg
    #pragma unroll
    for (int i = 0; i < 4; i++) {
        #pragma unroll
        for (int j = 0; j < 4; j++) {
            #pragma unroll
            for (int r = 0; r < 4; r++) {
                int gm = m0 + wm * 64 + i * 16 + lk * 4 + r;
                int gn = n0 + wn * 64 + j * 16 + lr;
                float v = acc[i][j][r] + bias[gn];
                int sel = gn >> 10;
                int rem = gn & 1023;
                int h   = rem >> 6;
                int hd  = rem & 63;
                int bb  = gm >> 11;
                int t   = gm & 2047;
                if (sel == 0)
                    Qb[((bb * NH + h) * SEQ + t) * HD + hd] = (bf16)(v * QSCALE);
                else if (sel == 1)
                    Kb[((bb * NH + h) * SEQ + t) * HD + hd] = (bf16)v;
                else
                    VbT[((bb * NH + h) * HD + hd) * SEQ + t] = (bf16)v;
            }
        }
    }
}

// ---------------------------------------------------------------------------
// Kernel 2: causal flash attention. 128 q-rows per block (wave owns 32),
// K-tiles of 64. V read pre-transposed -> pure b128 staging, no LDS scatter.
// Work-balance: qt = (bh>>4) ? 15-x : x  (paired so per-CU sums are equal
// under round-robin dispatch).  2 barriers per k-tile; Ps is wave-local.
// ---------------------------------------------------------------------------
__global__ __launch_bounds__(256)
void k_attn(const bf16* __restrict__ Qb, const bf16* __restrict__ Kb,
            const bf16* __restrict__ VbT, bf16* __restrict__ AO)
{
    __shared__ bf16 Ks[64][72];
    __shared__ bf16 Vt[64][72];    // [hd][key]
    __shared__ bf16 Ps[128][72];   // [q][key], wave-local 32-row strips

    const int tid  = threadIdx.x;
    const int wv   = tid >> 6;
    const int lane = tid & 63;
    const int lr   = lane & 15;
    const int lk   = lane >> 4;
    const int bh   = blockIdx.y;
    const int qt   = (bh >> 4) ? (15 - blockIdx.x) : blockIdx.x;  // 128-row q-tile

    const bf16* Qp  = Qb  + (size_t)bh * SEQ * HD;
    const bf16* Kp  = Kb  + (size_t)bh * SEQ * HD;
    const bf16* Vtp = VbT + (size_t)bh * HD * SEQ;

    const int qbase = qt * 128 + wv * 32;

    // Q fragments straight from global (A-frag: row=lr, k=lk*8+e)
    bf16x8 qa[2][2];
    #pragma unroll
    for (int h = 0; h < 2; h++)
        #pragma unroll
        for (int c = 0; c < 2; c++)
            qa[h][c] = *(const bf16x8*)&Qp[(size_t)(qbase + h * 16 + lr) * HD + c * 32 + lk * 8];

    f32x4 o[2][4] = {};
    float m_[2][4], l_[2][4];
    #pragma unroll
    for (int h = 0; h < 2; h++)
        #pragma unroll
        for (int r = 0; r < 4; r++) { m_[h][r] = NEGBIG; l_[h][r] = 0.f; }

    const int r0 = tid >> 3;          // 0..31
    const int c0 = (tid & 7) * 8;     // 0..56
    const int ktmax = 2 * qt + 1;

    for (int kt = 0; kt <= ktmax; kt++) {
        const int k0 = kt * 64;
        __syncthreads();
        *(bf16x8*)&Ks[r0     ][c0] = *(const bf16x8*)&Kp[(size_t)(k0 + r0     ) * HD + c0];
        *(bf16x8*)&Ks[r0 + 32][c0] = *(const bf16x8*)&Kp[(size_t)(k0 + r0 + 32) * HD + c0];
        *(bf16x8*)&Vt[r0     ][c0] = *(const bf16x8*)&Vtp[(size_t)(r0     ) * SEQ + k0 + c0];
        *(bf16x8*)&Vt[r0 + 32][c0] = *(const bf16x8*)&Vtp[(size_t)(r0 + 32) * SEQ + k0 + c0];
        __syncthreads();

        // S = Q K^T  (two 16-row strips per wave; scale folded into Q, log2 domain)
        f32x4 s[2][4] = {};
        #pragma unroll
        for (int j = 0; j < 4; j++) {
            #pragma unroll
            for (int c = 0; c < 2; c++) {
                bf16x8 kb = *(const bf16x8*)&Ks[j * 16 + lr][c * 32 + lk * 8];
                s[0][j] = MFMA16(qa[0][c], kb, s[0][j]);
                s[1][j] = MFMA16(qa[1][c], kb, s[1][j]);
            }
        }

        if (kt >= 2 * qt) {   // boundary tiles: elementwise causal mask
            #pragma unroll
            for (int h = 0; h < 2; h++) {
                int qg = qbase + h * 16 + lk * 4;
                #pragma unroll
                for (int j = 0; j < 4; j++) {
                    int kg = k0 + j * 16 + lr;
                    #pragma unroll
                    for (int r = 0; r < 4; r++)
                        if (kg > qg + r) s[h][j][r] = NEGBIG;
                }
            }
        }

        // online softmax: row (h,r) lives on the 16 lanes sharing lk
        #pragma unroll
        for (int h = 0; h < 2; h++) {
            #pragma unroll
            for (int r = 0; r < 4; r++) {
                float v = fmaxf(fmaxf(s[h][0][r], s[h][1][r]), fmaxf(s[h][2][r], s[h][3][r]));
                v = fmaxf(v, __shfl_xor(v, 1));
                v = fmaxf(v, __shfl_xor(v, 2));
                v = fmaxf(v, __shfl_xor(v, 4));
                v = fmaxf(v, __shfl_xor(v, 8));
                float mnew  = fmaxf(m_[h][r], v);
                float alpha = exp2f(m_[h][r] - mnew);
                m_[h][r] = mnew;
                float rsum = 0.f;
                #pragma unroll
                for (int j = 0; j < 4; j++) {
                    float p = exp2f(s[h][j][r] - mnew);
                    s[h][j][r] = p;
                    rsum += p;
                }
                rsum += __shfl_xor(rsum, 1);
                rsum += __shfl_xor(rsum, 2);
                rsum += __shfl_xor(rsum, 4);
                rsum += __shfl_xor(rsum, 8);
                l_[h][r] = l_[h][r] * alpha + rsum;
                #pragma unroll
                for (int jh = 0; jh < 4; jh++) o[h][jh][r] *= alpha;
            }
        }

        // P (C-layout) -> LDS (wave-local strip; no barrier needed)
        #pragma unroll
        for (int h = 0; h < 2; h++)
            #pragma unroll
            for (int j = 0; j < 4; j++)
                #pragma unroll
                for (int r = 0; r < 4; r++)
                    Ps[wv * 32 + h * 16 + lk * 4 + r][j * 16 + lr] = (bf16)s[h][j][r];

        // O += P V   (B operand = Vt rows [hd][key])
        #pragma unroll
        for (int c = 0; c < 2; c++) {
            bf16x8 pa0 = *(const bf16x8*)&Ps[wv * 32      + lr][c * 32 + lk * 8];
            bf16x8 pa1 = *(const bf16x8*)&Ps[wv * 32 + 16 + lr][c * 32 + lk * 8];
            #pragma unroll
            for (int jh = 0; jh < 4; jh++) {
                bf16x8 vb = *(const bf16x8*)&Vt[jh * 16 + lr][c * 32 + lk * 8];
                o[0][jh] = MFMA16(pa0, vb, o[0][jh]);
                o[1][jh] = MFMA16(pa1, vb, o[1][jh]);
            }
        }
    }

    // epilogue: AO[b, q, h_*64+hd] = O / l
    const int b_ = bh >> 4, h_ = bh & 15;
    #pragma unroll
    for (int h = 0; h < 2; h++) {
        #pragma unroll
        for (int r = 0; r < 4; r++) {
            float inv = 1.0f / l_[h][r];
            int q = qbase + h * 16 + lk * 4 + r;
            size_t base = ((size_t)(b_ * SEQ + q)) * D_MODEL + h_ * HD;
            #pragma unroll
            for (int jh = 0; jh < 4; jh++)
                AO[base + jh * 16 + lr] = (bf16)(o[h][jh][r] * inv);
        }
    }
}

// ---------------------------------------------------------------------------
// Kernel 3: output projection, 128x128 tile. A bf16 (workspace), W f32->bf16
// in staging, out f32 coalesced.
// ---------------------------------------------------------------------------
__global__ __launch_bounds__(256)
void k_oproj(const bf16* __restrict__ a_, const float* __restrict__ w,
             const float* __restrict__ bias, float* __restrict__ out)
{
    __shared__ bf16 As[128][40];
    __shared__ bf16 Ws[128][40];

    const int tid  = threadIdx.x;
    const int wv   = tid >> 6;
    const int lane = tid & 63;
    const int lr   = lane & 15;
    const int lk   = lane >> 4;
    const int wm   = wv >> 1, wn = wv & 1;
    const int m0   = blockIdx.x * 128;
    const int n0   = blockIdx.y * 128;

    const int ldRow = tid >> 2;
    const int ldCh  = (tid & 3) * 8;

    f32x4 acc[4][4] = {};

    for (int kt = 0; kt < 1024; kt += 32) {
        __syncthreads();
        *(bf16x8*)&As[ldRow     ][ldCh] = *(const bf16x8*)&a_[(size_t)(m0 + ldRow     ) * 1024 + kt + ldCh];
        *(bf16x8*)&As[ldRow + 64][ldCh] = *(const bf16x8*)&a_[(size_t)(m0 + ldRow + 64) * 1024 + kt + ldCh];
        *(bf16x8*)&Ws[ldRow     ][ldCh] = cvt8(&w[(size_t)(n0 + ldRow     ) * 1024 + kt + ldCh]);
        *(bf16x8*)&Ws[ldRow + 64][ldCh] = cvt8(&w[(size_t)(n0 + ldRow + 64) * 1024 + kt + ldCh]);
        __syncthreads();

        bf16x8 a[4], b[4];
        #pragma unroll
        for (int i = 0; i < 4; i++) {
            a[i] = *(const bf16x8*)&As[wm * 64 + i * 16 + lr][lk * 8];
            b[i] = *(const bf16x8*)&Ws[wn * 64 + i * 16 + lr][lk * 8];
        }
        #pragma unroll
        for (int i = 0; i < 4; i++)
            #pragma unroll
            for (int j = 0; j < 4; j++)
                acc[i][j] = MFMA16(a[i], b[j], acc[i][j]);
    }

    #pragma unroll
    for (int i = 0; i < 4; i++) {
        #pragma unroll
        for (int j = 0; j < 4; j++) {
            #pragma unroll
            for (int r = 0; r < 4; r++) {
                int gm = m0 + wm * 64 + i * 16 + lk * 4 + r;
                int gn = n0 + wn * 64 + j * 16 + lr;
                out[(size_t)gm * 1024 + gn] = acc[i][j][r] + bias[gn];
            }
        }
    }
}

// ---------------------------------------------------------------------------
extern "C" void kernel_launch(void* const* d_in, const int* in_sizes, int n_in,
                              void* d_out, int out_size, void* d_ws, size_t ws_size,
                              hipStream_t stream)
{
    const float* x     = (const float*)d_in[0];
    const float* qkv_w = (const float*)d_in[1];
    const float* qkv_b = (const float*)d_in[2];
    const float* out_w = (const float*)d_in[3];
    const float* out_b = (const float*)d_in[4];
    float* out = (float*)d_out;

    // workspace: Qb | Kb | VbT | AO, each 4,194,304 bf16 (8 MB) -> 32 MB total
    const size_t SZ = (size_t)NB * NH * SEQ * HD;
    bf16* Qb  = (bf16*)d_ws;
    bf16* Kb  = Qb + SZ;
    bf16* VbT = Kb + SZ;
    bf16* AO  = VbT + SZ;

    hipLaunchKernelGGL(k_qkv, dim3(32, 24), dim3(256), 0, stream,
                       x, qkv_w, qkv_b, Qb, Kb, VbT);
    hipLaunchKernelGGL(k_attn, dim3(16, 32), dim3(256), 0, stream,
                       Qb, Kb, VbT, AO);
    hipLaunchKernelGGL(k_oproj, dim3(32, 8), dim3(256), 0, stream,
                       AO, out_w, out_b, out);
}

// Round 4
// 225.600 us; speedup vs baseline: 1.4926x; 1.2597x over previous
//
#include <hip/hip_runtime.h>
#include <hip/hip_bf16.h>

// B=2, T=2048, D=1024, H=16, Hd=64. Inputs/outputs f32; compute bf16 MFMA.

typedef __bf16 bf16;
typedef bf16 bf16x8 __attribute__((ext_vector_type(8)));
typedef bf16 bf16x4 __attribute__((ext_vector_type(4)));
typedef float f32x4 __attribute__((ext_vector_type(4)));

#define MFMA16(a, b, c) __builtin_amdgcn_mfma_f32_16x16x32_bf16((a), (b), (c), 0, 0, 0)

static constexpr int D_MODEL = 1024;
static constexpr int NH = 16;
static constexpr int HD = 64;
static constexpr int SEQ = 2048;
static constexpr int NB = 2;
static constexpr float QSCALE = 0.125f * 1.44269504088896340736f; // 1/sqrt(64)*log2(e)
static constexpr float NEGBIG = -1.0e30f;

__device__ __forceinline__ bf16x8 cvt8(const float* p) {
    float4 u0 = *(const float4*)p;
    float4 u1 = *(const float4*)(p + 4);
    bf16x8 v = { (bf16)u0.x, (bf16)u0.y, (bf16)u0.z, (bf16)u0.w,
                 (bf16)u1.x, (bf16)u1.y, (bf16)u1.z, (bf16)u1.w };
    return v;
}

// ---------------------------------------------------------------------------
// Kernel 1: QKV projection, 128x128 tile, BK=32, 4 waves 2x2.
// Q -> [B,H,T,64] (pre-scaled), K -> [B,H,T,64], V -> transposed [B,H,64,T]
// (V^T stores packed as b64 along T).
// ---------------------------------------------------------------------------
__global__ __launch_bounds__(256)
void k_qkv(const float* __restrict__ x, const float* __restrict__ w,
           const float* __restrict__ bias,
           bf16* __restrict__ Qb, bf16* __restrict__ Kb, bf16* __restrict__ VbT)
{
    __shared__ bf16 As[128][40];
    __shared__ bf16 Ws[128][40];

    const int tid  = threadIdx.x;
    const int wv   = tid >> 6;
    const int lane = tid & 63;
    const int lr   = lane & 15;
    const int lk   = lane >> 4;
    const int wm   = wv >> 1, wn = wv & 1;
    const int m0   = blockIdx.x * 128;
    const int n0   = blockIdx.y * 128;

    const int ldRow = tid >> 2;          // 0..63
    const int ldCh  = (tid & 3) * 8;     // 0,8,16,24

    f32x4 acc[4][4] = {};

    for (int kt = 0; kt < 1024; kt += 32) {
        __syncthreads();
        *(bf16x8*)&As[ldRow     ][ldCh] = cvt8(&x[(size_t)(m0 + ldRow     ) * 1024 + kt + ldCh]);
        *(bf16x8*)&As[ldRow + 64][ldCh] = cvt8(&x[(size_t)(m0 + ldRow + 64) * 1024 + kt + ldCh]);
        *(bf16x8*)&Ws[ldRow     ][ldCh] = cvt8(&w[(size_t)(n0 + ldRow     ) * 1024 + kt + ldCh]);
        *(bf16x8*)&Ws[ldRow + 64][ldCh] = cvt8(&w[(size_t)(n0 + ldRow + 64) * 1024 + kt + ldCh]);
        __syncthreads();

        bf16x8 a[4], b[4];
        #pragma unroll
        for (int i = 0; i < 4; i++) {
            a[i] = *(const bf16x8*)&As[wm * 64 + i * 16 + lr][lk * 8];
            b[i] = *(const bf16x8*)&Ws[wn * 64 + i * 16 + lr][lk * 8];
        }
        #pragma unroll
        for (int i = 0; i < 4; i++)
            #pragma unroll
            for (int j = 0; j < 4; j++)
                acc[i][j] = MFMA16(a[i], b[j], acc[i][j]);
    }

    // C/D layout: col = lane&15, row = (lane>>4)*4 + reg
    #pragma unroll
    for (int i = 0; i < 4; i++) {
        #pragma unroll
        for (int j = 0; j < 4; j++) {
            const int gm0 = m0 + wm * 64 + i * 16 + lk * 4;   // r=0..3 consecutive
            const int gn  = n0 + wn * 64 + j * 16 + lr;
            const int sel = gn >> 10;
            const int rem = gn & 1023;
            const int h   = rem >> 6;
            const int hd  = rem & 63;
            const int bb  = gm0 >> 11;
            const int t0  = gm0 & 2047;
            if (sel == 2) {
                bf16x4 p;
                #pragma unroll
                for (int r = 0; r < 4; r++) p[r] = (bf16)(acc[i][j][r] + bias[gn]);
                *(bf16x4*)&VbT[((size_t)(bb * NH + h) * HD + hd) * SEQ + t0] = p;
            } else {
                #pragma unroll
                for (int r = 0; r < 4; r++) {
                    float v = acc[i][j][r] + bias[gn];
                    size_t idx = ((size_t)(bb * NH + h) * SEQ + t0 + r) * HD + hd;
                    if (sel == 0) Qb[idx] = (bf16)(v * QSCALE);
                    else          Kb[idx] = (bf16)v;
                }
            }
        }
    }
}

// ---------------------------------------------------------------------------
// Kernel 2: causal flash attention, transposed-score formulation.
// Block = 64 q-rows, 4 waves (wave owns 16 q). S^T = K·Q^T so each lane holds
// 16 scores of ONE q -> softmax is in-lane + 2 shfls. O accumulated as O^T.
// Grid (32, B*H); qt flipped by ((bh>>3)&1) for per-CU balance.
// ---------------------------------------------------------------------------
__global__ __launch_bounds__(256)
void k_attn(const bf16* __restrict__ Qb, const bf16* __restrict__ Kb,
            const bf16* __restrict__ VbT, bf16* __restrict__ AO)
{
    __shared__ bf16 Ks[64][72];
    __shared__ bf16 Vt[64][72];    // [hd][key]
    __shared__ bf16 Ps[64][72];    // [q][key], wave-local 16-row strips

    const int tid  = threadIdx.x;
    const int wv   = tid >> 6;
    const int lane = tid & 63;
    const int lr   = lane & 15;
    const int lk   = lane >> 4;
    const int bh   = blockIdx.y;
    const int qt   = ((bh >> 3) & 1) ? (31 - (int)blockIdx.x) : (int)blockIdx.x;

    const bf16* Qp  = Qb  + (size_t)bh * SEQ * HD;
    const bf16* Kp  = Kb  + (size_t)bh * SEQ * HD;
    const bf16* Vtp = VbT + (size_t)bh * HD * SEQ;

    const int qg = qt * 64 + wv * 16 + lr;    // this lane's query row

    // Q as B-operand: b[n=lr][k=lk*8+e]  (loop-invariant)
    bf16x8 qf[2];
    qf[0] = *(const bf16x8*)&Qp[(size_t)qg * HD +      lk * 8];
    qf[1] = *(const bf16x8*)&Qp[(size_t)qg * HD + 32 + lk * 8];

    f32x4 ot[4] = {};          // O^T: col=q(=lr), row=hd=jh*16+lk*4+r
    float m_ = NEGBIG, l_ = 0.f;

    const int r0 = tid >> 3;          // 0..31
    const int c0 = (tid & 7) * 8;

    for (int kt = 0; kt <= qt; kt++) {
        const int k0 = kt * 64;
        __syncthreads();
        *(bf16x8*)&Ks[r0     ][c0] = *(const bf16x8*)&Kp[(size_t)(k0 + r0     ) * HD + c0];
        *(bf16x8*)&Ks[r0 + 32][c0] = *(const bf16x8*)&Kp[(size_t)(k0 + r0 + 32) * HD + c0];
        *(bf16x8*)&Vt[r0     ][c0] = *(const bf16x8*)&Vtp[(size_t)(r0     ) * SEQ + k0 + c0];
        *(bf16x8*)&Vt[r0 + 32][c0] = *(const bf16x8*)&Vtp[(size_t)(r0 + 32) * SEQ + k0 + c0];
        __syncthreads();

        // S^T[key][q]: A = K rows, B = Q rows. row=key=lk*4+r (per j-strip), col=q=lr.
        f32x4 s[4] = {};
        #pragma unroll
        for (int j = 0; j < 4; j++) {
            #pragma unroll
            for (int c = 0; c < 2; c++) {
                bf16x8 ka = *(const bf16x8*)&Ks[j * 16 + lr][c * 32 + lk * 8];
                s[j] = MFMA16(ka, qf[c], s[j]);
            }
        }

        if (kt == qt) {   // diagonal tile: elementwise causal mask
            #pragma unroll
            for (int j = 0; j < 4; j++) {
                int keyb = k0 + j * 16 + lk * 4;
                #pragma unroll
                for (int r = 0; r < 4; r++)
                    if (keyb + r > qg) s[j][r] = NEGBIG;
            }
        }

        // softmax over keys for this lane's q: 16 in-lane + 2 shfls each
        float v01 = fmaxf(fmaxf(s[0][0], s[0][1]), fmaxf(s[0][2], s[0][3]));
        float v23 = fmaxf(fmaxf(s[1][0], s[1][1]), fmaxf(s[1][2], s[1][3]));
        float v45 = fmaxf(fmaxf(s[2][0], s[2][1]), fmaxf(s[2][2], s[2][3]));
        float v67 = fmaxf(fmaxf(s[3][0], s[3][1]), fmaxf(s[3][2], s[3][3]));
        float v = fmaxf(fmaxf(v01, v23), fmaxf(v45, v67));
        v = fmaxf(v, __shfl_xor(v, 16));
        v = fmaxf(v, __shfl_xor(v, 32));
        float mnew  = fmaxf(m_, v);
        float alpha = exp2f(m_ - mnew);
        m_ = mnew;

        float rs = 0.f;
        #pragma unroll
        for (int j = 0; j < 4; j++) {
            #pragma unroll
            for (int r = 0; r < 4; r++) {
                float p = exp2f(s[j][r] - mnew);
                s[j][r] = p;
                rs += p;
            }
        }
        rs += __shfl_xor(rs, 16);
        rs += __shfl_xor(rs, 32);
        l_ = l_ * alpha + rs;
        #pragma unroll
        for (int jh = 0; jh < 4; jh++)
            #pragma unroll
            for (int r = 0; r < 4; r++) ot[jh][r] *= alpha;

        // P -> LDS [q][key], packed b64; wave-local rows (no barrier needed)
        #pragma unroll
        for (int j = 0; j < 4; j++) {
            bf16x4 p4 = { (bf16)s[j][0], (bf16)s[j][1], (bf16)s[j][2], (bf16)s[j][3] };
            *(bf16x4*)&Ps[wv * 16 + lr][j * 16 + lk * 4] = p4;
        }

        // O^T += Vt · P^T : MFMA(a = Vt rows [hd][key], b = Ps rows [q][key])
        #pragma unroll
        for (int c = 0; c < 2; c++) {
            bf16x8 pb = *(const bf16x8*)&Ps[wv * 16 + lr][c * 32 + lk * 8];
            #pragma unroll
            for (int jh = 0; jh < 4; jh++) {
                bf16x8 va = *(const bf16x8*)&Vt[jh * 16 + lr][c * 32 + lk * 8];
                ot[jh] = MFMA16(va, pb, ot[jh]);
            }
        }
    }

    // epilogue: AO[b, q, h_*64 + hd] = O/l ; lane writes 4 consecutive hd (b64)
    const float inv = 1.0f / l_;
    const int b_ = bh >> 4, h_ = bh & 15;
    const size_t base = ((size_t)(b_ * SEQ + qg)) * D_MODEL + h_ * HD;
    #pragma unroll
    for (int jh = 0; jh < 4; jh++) {
        bf16x4 o4 = { (bf16)(ot[jh][0] * inv), (bf16)(ot[jh][1] * inv),
                      (bf16)(ot[jh][2] * inv), (bf16)(ot[jh][3] * inv) };
        *(bf16x4*)&AO[base + jh * 16 + lk * 4] = o4;
    }
}

// ---------------------------------------------------------------------------
// Kernel 3: output projection, 128x64 tile (wave = 64x32), grid 512 blocks.
// ---------------------------------------------------------------------------
__global__ __launch_bounds__(256)
void k_oproj(const bf16* __restrict__ a_, const float* __restrict__ w,
             const float* __restrict__ bias, float* __restrict__ out)
{
    __shared__ bf16 As[128][40];
    __shared__ bf16 Ws[64][40];

    const int tid  = threadIdx.x;
    const int wv   = tid >> 6;
    const int lane = tid & 63;
    const int lr   = lane & 15;
    const int lk   = lane >> 4;
    const int wm   = wv >> 1, wn = wv & 1;
    const int m0   = blockIdx.x * 128;
    const int n0   = blockIdx.y * 64;

    const int ldRow = tid >> 2;          // 0..63
    const int ldCh  = (tid & 3) * 8;

    f32x4 acc[4][2] = {};

    for (int kt = 0; kt < 1024; kt += 32) {
        __syncthreads();
        *(bf16x8*)&As[ldRow     ][ldCh] = *(const bf16x8*)&a_[(size_t)(m0 + ldRow     ) * 1024 + kt + ldCh];
        *(bf16x8*)&As[ldRow + 64][ldCh] = *(const bf16x8*)&a_[(size_t)(m0 + ldRow + 64) * 1024 + kt + ldCh];
        *(bf16x8*)&Ws[ldRow][ldCh] = cvt8(&w[(size_t)(n0 + ldRow) * 1024 + kt + ldCh]);
        __syncthreads();

        bf16x8 a[4], b[2];
        #pragma unroll
        for (int i = 0; i < 4; i++)
            a[i] = *(const bf16x8*)&As[wm * 64 + i * 16 + lr][lk * 8];
        #pragma unroll
        for (int j = 0; j < 2; j++)
            b[j] = *(const bf16x8*)&Ws[wn * 32 + j * 16 + lr][lk * 8];
        #pragma unroll
        for (int i = 0; i < 4; i++)
            #pragma unroll
            for (int j = 0; j < 2; j++)
                acc[i][j] = MFMA16(a[i], b[j], acc[i][j]);
    }

    #pragma unroll
    for (int i = 0; i < 4; i++) {
        #pragma unroll
        for (int j = 0; j < 2; j++) {
            #pragma unroll
            for (int r = 0; r < 4; r++) {
                int gm = m0 + wm * 64 + i * 16 + lk * 4 + r;
                int gn = n0 + wn * 32 + j * 16 + lr;
                out[(size_t)gm * 1024 + gn] = acc[i][j][r] + bias[gn];
            }
        }
    }
}

// ---------------------------------------------------------------------------
extern "C" void kernel_launch(void* const* d_in, const int* in_sizes, int n_in,
                              void* d_out, int out_size, void* d_ws, size_t ws_size,
                              hipStream_t stream)
{
    const float* x     = (const float*)d_in[0];
    const float* qkv_w = (const float*)d_in[1];
    const float* qkv_b = (const float*)d_in[2];
    const float* out_w = (const float*)d_in[3];
    const float* out_b = (const float*)d_in[4];
    float* out = (float*)d_out;

    // workspace: Qb | Kb | VbT | AO, each 4,194,304 bf16 (8 MB) -> 32 MB total
    const size_t SZ = (size_t)NB * NH * SEQ * HD;
    bf16* Qb  = (bf16*)d_ws;
    bf16* Kb  = Qb + SZ;
    bf16* VbT = Kb + SZ;
    bf16* AO  = VbT + SZ;

    hipLaunchKernelGGL(k_qkv, dim3(32, 24), dim3(256), 0, stream,
                       x, qkv_w, qkv_b, Qb, Kb, VbT);
    hipLaunchKernelGGL(k_attn, dim3(32, 32), dim3(256), 0, stream,
                       Qb, Kb, VbT, AO);
    hipLaunchKernelGGL(k_oproj, dim3(32, 16), dim3(256), 0, stream,
                       AO, out_w, out_b, out);
}